// Round 10
// baseline (34.627 us; speedup 1.0000x reference)
//
#include <hip/hip_runtime.h>

// LSTM B=65536, T=9, I=57, H=2 (4H=8) — single-kernel, block-local two-phase.
//
// R8 (33.7us) post-mortem: LDS pipe ~13us/CU, half of it the 14 ds_bpermute
// per wave-chunk from __shfl rotate-reduce. R9: DPP rotate-reduce, but with
// row_ror direction reversed -> absmax 6.8e-2. That failure empirically fixed
// the ISA convention: row_ror:N is dst[i] = src[(i-N)&15]. Correct control for
// "gate g gathers acc[d] from gate (g-d), same parity" is row_ror:(2d).
// Lane layout per 16-lane DPP row: l = 2*g + p (g=gate 0..7, p=batch parity).

#define B_TOTAL 65536
#define T_STEPS 9
#define I_DIM   57
#define BATCH_PER_BLOCK 64
#define ROWS_PER_BLOCK (BATCH_PER_BLOCK * T_STEPS)   // 576
#define CHUNK_ROWS 64
#define N_CHUNKS   (ROWS_PER_BLOCK / CHUNK_ROWS)     // 9
#define CHUNK_DW   (CHUNK_ROWS * I_DIM)              // 3648 dwords, 14592 B
#define CHUNK_F4   (CHUNK_DW / 4)                    // 912
#define GX_PAD     9                                  // 8 gates + 1 pad
#define NBLOCKS    (B_TOTAL / BATCH_PER_BLOCK)       // 1024

__device__ __forceinline__ float fast_tanh(float v) {
    // tanh(v) = 1 - 2/(exp(2v)+1); exp(2v) = exp2(2*log2e*v). Err ~1e-6.
    float e = __builtin_amdgcn_exp2f(2.885390082f * v);
    return 1.0f - 2.0f * __builtin_amdgcn_rcpf(e + 1.0f);
}
__device__ __forceinline__ float fast_sig(float v) {
    return 0.5f * fast_tanh(0.5f * v) + 0.5f;
}

// row_ror:N within 16-lane DPP rows; CTRL = 0x120 | N (compile-time const).
// Semantics (established by R9 failure): dst[i] = src[(i-N)&15].
#define DPP_ROR_F32(VAR, SRC, CTRL)                                          \
    float VAR = __builtin_bit_cast(float, __builtin_amdgcn_update_dpp(       \
        0, __builtin_bit_cast(int, SRC), (CTRL), 0xF, 0xF, false))

__global__ __launch_bounds__(256)
void lstm_onepass(const float* __restrict__ x,
                  const float* __restrict__ W_ih,
                  const float* __restrict__ W_hh,
                  const float* __restrict__ b_ih,
                  const float* __restrict__ b_hh,
                  const float* __restrict__ fc_w,
                  const float* __restrict__ fc_b,
                  float* __restrict__ out) {
    __shared__ float xs[2][CHUNK_DW];                 // 29184 B staging dbuf
    __shared__ float gxp[ROWS_PER_BLOCK * GX_PAD];    // 20736 B gate pre-acts

    const int tid  = threadIdx.x;
    const int wv   = tid >> 6;          // wave 0..3
    const int cl   = (tid >> 4) & 3;    // 16-lane cluster (DPP row) 0..3
    const int g    = (tid >> 1) & 7;    // gate lane 0..7
    const int p    = tid & 1;           // batch parity (row-within-cluster)

    // Rotated weight slices: acc[d] accumulates gate (g+d)&7 over slice {g+8k}.
    // wrot[d][7] pairs with broadcast x[56]; only g==0 lane contributes.
    float wrot[8][8];
#pragma unroll
    for (int d = 0; d < 8; ++d) {
        const int gg = (g + d) & 7;
        const float* wr = W_ih + gg * I_DIM;
#pragma unroll
        for (int k = 0; k < 7; ++k) wrot[d][k] = wr[g + 8 * k];
        wrot[d][7] = (g == 0) ? wr[56] : 0.0f;
    }
    float bsum = b_ih[g] + b_hh[g];
#pragma unroll
    for (int d = 0; d < 8; ++d)
#pragma unroll
        for (int k = 0; k < 8; ++k)
            asm volatile("" : "+v"(wrot[d][k]));

    // Block's x tile: 576 rows contiguous, 16B-aligned (576*228 % 16 == 0).
    const float* xblk = x + (size_t)blockIdx.x * (ROWS_PER_BLOCK * I_DIM);

    float4 st0, st1, st2, st3;

#define STAGE_LOAD(C) do {                                                  \
        const float4* xc_ = (const float4*)(xblk + (size_t)(C) * CHUNK_DW); \
        st0 = xc_[tid];                                                     \
        st1 = xc_[256 + tid];                                               \
        st2 = xc_[512 + tid];                                               \
        if (tid < CHUNK_F4 - 768) st3 = xc_[768 + tid];                     \
    } while (0)

#define STAGE_WRITE(S) do {                                                 \
        float4* L_ = (float4*)xs[S];                                        \
        L_[tid] = st0;                                                      \
        L_[256 + tid] = st1;                                                \
        L_[512 + tid] = st2;                                                \
        if (tid < CHUNK_F4 - 768) L_[768 + tid] = st3;                      \
    } while (0)

    // Compute 2 rows per thread of chunk C from buffer S.
    // Wave covers rows [wv*16, wv*16+16): iter i -> row wv*16 + i*8 + cl*2 + p.
#define COMPUTE(S, C) do {                                                  \
        _Pragma("unroll")                                                   \
        for (int iter = 0; iter < 2; ++iter) {                              \
            const int rl_ = wv * 16 + iter * 8 + cl * 2 + p;                \
            const float* row_ = xs[S] + rl_ * I_DIM;                        \
            float xv_[8];                                                   \
            _Pragma("unroll")                                               \
            for (int k = 0; k < 7; ++k) xv_[k] = row_[g + 8 * k];           \
            xv_[7] = row_[56];   /* broadcast; pairs with wrot[d][7] */     \
            float acc_[8];                                                  \
            _Pragma("unroll")                                               \
            for (int d = 0; d < 8; ++d) {                                   \
                float s_ = wrot[d][0] * xv_[0];                             \
                _Pragma("unroll")                                           \
                for (int k = 1; k < 8; ++k) s_ += wrot[d][k] * xv_[k];      \
                acc_[d] = s_;                                               \
            }                                                               \
            /* DPP rotate-gather: gate g takes acc[d] from gate (g-d)&7,    \
               same parity: row_ror:(2d), dst[i]=src[(i-2d)&15]. */         \
            DPP_ROR_F32(r1_, acc_[1], 0x122);                               \
            DPP_ROR_F32(r2_, acc_[2], 0x124);                               \
            DPP_ROR_F32(r3_, acc_[3], 0x126);                               \
            DPP_ROR_F32(r4_, acc_[4], 0x128);                               \
            DPP_ROR_F32(r5_, acc_[5], 0x12A);                               \
            DPP_ROR_F32(r6_, acc_[6], 0x12C);                               \
            DPP_ROR_F32(r7_, acc_[7], 0x12E);                               \
            float tot_ = ((acc_[0] + r1_) + (r2_ + r3_))                    \
                       + ((r4_ + r5_) + (r6_ + r7_)) + bsum;                \
            gxp[((C) * CHUNK_ROWS + rl_) * GX_PAD + g] = tot_;              \
        }                                                                   \
    } while (0)

    STAGE_LOAD(0);
    STAGE_WRITE(0);

#pragma unroll
    for (int cc = 0; cc < N_CHUNKS; ++cc) {
        __syncthreads();                               // xs[cc&1] ready
        if (cc + 1 < N_CHUNKS) STAGE_LOAD(cc + 1);     // issue early
        COMPUTE(cc & 1, cc);                           // hides HBM latency
        if (cc + 1 < N_CHUNKS) STAGE_WRITE((cc + 1) & 1);
    }
#undef STAGE_LOAD
#undef STAGE_WRITE
#undef COMPUTE

    __syncthreads();   // gxp complete

    // ---------------- Phase B: recurrence, one wave, 1 thread/batch --------
    if (tid < BATCH_PER_BLOCK) {
        float w0[8], w1[8];
#pragma unroll
        for (int q = 0; q < 8; ++q) {
            w0[q] = W_hh[q * 2];
            w1[q] = W_hh[q * 2 + 1];
        }

        float h0 = 0.f, h1 = 0.f, c0 = 0.f, c1 = 0.f;
        const float* gb = gxp + tid * (T_STEPS * GX_PAD);  // stride 81 floats

#pragma unroll
        for (int t = 0; t < T_STEPS; ++t) {
            const float* pp = gb + t * GX_PAD;
            // gate rows [i0,i1,f0,f1,g0,g1,o0,o1]
            const float i0 = fast_sig (pp[0] + h0 * w0[0] + h1 * w1[0]);
            const float i1 = fast_sig (pp[1] + h0 * w0[1] + h1 * w1[1]);
            const float f0 = fast_sig (pp[2] + h0 * w0[2] + h1 * w1[2]);
            const float f1 = fast_sig (pp[3] + h0 * w0[3] + h1 * w1[3]);
            const float g0 = fast_tanh(pp[4] + h0 * w0[4] + h1 * w1[4]);
            const float g1 = fast_tanh(pp[5] + h0 * w0[5] + h1 * w1[5]);
            const float o0 = fast_sig (pp[6] + h0 * w0[6] + h1 * w1[6]);
            const float o1 = fast_sig (pp[7] + h0 * w0[7] + h1 * w1[7]);
            c0 = f0 * c0 + i0 * g0;
            c1 = f1 * c1 + i1 * g1;
            h0 = o0 * fast_tanh(c0);
            h1 = o1 * fast_tanh(c1);
        }

        out[blockIdx.x * BATCH_PER_BLOCK + tid] =
            h0 * fc_w[0] + h1 * fc_w[1] + fc_b[0];
    }
}

extern "C" void kernel_launch(void* const* d_in, const int* in_sizes, int n_in,
                              void* d_out, int out_size, void* d_ws, size_t ws_size,
                              hipStream_t stream) {
    const float* x    = (const float*)d_in[0];
    const float* W_ih = (const float*)d_in[1];
    const float* W_hh = (const float*)d_in[2];
    const float* b_ih = (const float*)d_in[3];
    const float* b_hh = (const float*)d_in[4];
    const float* fc_w = (const float*)d_in[5];
    const float* fc_b = (const float*)d_in[6];
    float* out = (float*)d_out;

    lstm_onepass<<<dim3(NBLOCKS), dim3(256), 0, stream>>>(
        x, W_ih, W_hh, b_ih, b_hh, fc_w, fc_b, out);
}